// Round 2
// baseline (92.331 us; speedup 1.0000x reference)
//
#include <hip/hip_runtime.h>

// Problem constants (fixed by the reference file)
#define BQ    64        // batches
#define NG    128       // nodes per batch
#define NE    65536     // input edges
#define TOPK  16
#define AUGE  (NE + BQ * TOPK)   // 66560 edges per row after augmentation
#define WORDS (NG * NG / 32)     // 512 words = 16384 bits = one batch's pair bitmap

#define NCOPY 32                 // copy blocks: 32 x 1024 threads = 32768 int4 = both rows
#define NBLK  (NCOPY + BQ)       // 96 blocks total, one launch

// Structural insight (verified, absmax 0 across all prior rounds): LayerNorm
// over the size-1 last axis makes scores == beta (constant) for ANY inputs —
// the MLP is dead code. top_k picks, per batch, the first TOPK row-major
// (sl,dl) pairs that are neither diagonal nor an existing same-batch edge
// (jax.lax.top_k tie-break: lowest flattened index).
//
// Round 7 (post-mortem of fused round 6): the 64-block fused kernel made
// every block stream the full 512 KB edge list -> ~3.8 us per CU, slower
// than the old two-kernel split. Fix, keeping ONE launch / zero workspace:
//   * 32 copy blocks move edge_index -> out (32768 int4, 8 KB/block/row),
//     fully parallel with everything else.
//   * 64 scan blocks (one per batch) read ONLY the src row linearly
//     (256 KB; L2-resident, ~1.8 us at the per-CU L2 port) and gather dst
//     scalars just for the ~1.6% of edges whose src matches their batch
//     (~1K latency-hidden L2 hits). Bits land in a 2 KB LDS bitmap;
//     thread 0 then emits the first TOPK clear bits.
// No cross-block communication, no ordering assumptions, no poison reliance.
__global__ __launch_bounds__(1024) void fused_kernel(
    const int4* __restrict__ src4, const int* __restrict__ dst,
    const int4* __restrict__ dst4, int* __restrict__ out)
{
    const int t = threadIdx.x;

    if (blockIdx.x < NCOPY) {
        // ---- copy role: flat int4 index over [src row | dst row] ----
        int flat = blockIdx.x * 1024 + t;            // 0..32767
        if (flat < 16384) {
            ((int4*)(out))[flat] = src4[flat];       // aug row 0 (src copy)
        } else {
            int i = flat - 16384;
            ((int4*)(out + AUGE))[i] = dst4[i];      // aug row 1 (dst copy)
        }
        if (blockIdx.x == 0 && t == 0)
            out[2 * AUGE] = BQ * TOPK;               // added_count = 1024
        return;
    }

    // ---- scan role: block owns batch g ----
    const int g = blockIdx.x - NCOPY;                // 0..63
    __shared__ unsigned bm[WORDS];   // bit idx = sl*128 + dl, 1 = excluded

    // Init bitmap with the diagonal pre-marked (sl == dl excluded).
    // Word w covers idx [w*32, w*32+32): sl = w>>2, dl in [(w&3)*32, +32).
    if (t < WORDS) {
        int sl  = t >> 2;
        int dlo = (t & 3) << 5;
        bm[t] = (sl >= dlo && sl < dlo + 32) ? (1u << (sl - dlo)) : 0u;
    }
    __syncthreads();

    // Scan the src row only: 16384 int4, 16 iterations x 1024 threads.
    // For each src element in batch g, gather the matching dst scalar and
    // set the exclusion bit. (Reference semantics: mark only same-batch
    // edges — we check the gathered dst's batch too; in this data it is
    // always equal by construction, so the gather rate is ~1.6%.)
    #pragma unroll 4
    for (int c = 0; c < 16; ++c) {
        int i  = (c << 10) + t;                      // int4 index 0..16383
        int4 s = src4[i];
        #define TRY(SS, J)                                                   \
            if (((SS) >> 7) == g) {                                          \
                int d = dst[(i << 2) | (J)];                                 \
                if ((d >> 7) == g) {                                         \
                    int idx = (((SS) & 127) << 7) | (d & 127);               \
                    atomicOr(&bm[idx >> 5], 1u << (idx & 31));               \
                }                                                            \
            }
        TRY(s.x, 0) TRY(s.y, 1) TRY(s.z, 2) TRY(s.w, 3)
        #undef TRY
    }
    __syncthreads();

    // Select: first TOPK clear bits in ascending idx (row-major tie-break of
    // jax.lax.top_k over a constant score field). Serial on thread 0 — the
    // answer is almost always within the first couple of words (~6% bit
    // density); worst case 512 LDS words is still trivial.
    if (t == 0) {
        int found = 0;
        for (int w = 0; w < WORDS && found < TOPK; ++w) {
            unsigned inv = ~bm[w];                   // 1 = free pair
            while (inv && found < TOPK) {
                int j = __ffs(inv) - 1;
                inv &= inv - 1;
                int idx = (w << 5) | j;
                out[NE   + (g << 4) + found]      = (g << 7) | (idx >> 7);  // src
                out[AUGE + NE + (g << 4) + found] = (g << 7) | (idx & 127); // dst
                ++found;
            }
        }
    }
}

extern "C" void kernel_launch(void* const* d_in, const int* in_sizes, int n_in,
                              void* d_out, int out_size, void* d_ws, size_t ws_size,
                              hipStream_t stream) {
    // Input order per setup_inputs():
    // 0:h 1:q 2:W1 3:b1 4:W2 5:b2 6:gamma 7:beta 8:edge_index 9:node_batch 10:top_k
    const int* edge_index = (const int*)d_in[8];
    const int4* e_src4 = (const int4*)edge_index;          // edge_index[0]
    const int*  e_dst  = edge_index + NE;                  // edge_index[1]
    const int4* e_dst4 = (const int4*)e_dst;

    int* out = (int*)d_out;   // int32 output, 2*AUGE + 1 elements

    // d_ws intentionally unused: no workspace, no poison-value assumptions.
    (void)d_ws; (void)ws_size;

    fused_kernel<<<dim3(NBLK), dim3(1024), 0, stream>>>(e_src4, e_dst, e_dst4, out);
}

// Round 3
// 76.165 us; speedup vs baseline: 1.2122x; 1.2122x over previous
//
#include <hip/hip_runtime.h>

// Problem constants (fixed by the reference file)
#define BQ    64        // batches
#define NG    128       // nodes per batch
#define NE    65536     // input edges
#define TOPK  16
#define AUGE  (NE + BQ * TOPK)   // 66560 edges per row after augmentation
#define MAGIC 0x55u     // "edge exists" tag (ws poison is 0xAA, fresh is 0x00 — both read as free)

// Structural insight (verified, absmax 0 across all rounds): LayerNorm over
// the size-1 last axis makes scores == beta (constant) for ANY inputs — the
// MLP is dead code. top_k picks, per batch, the first TOPK row-major (sl,dl)
// pairs that are neither diagonal nor an existing same-batch edge
// (jax.lax.top_k tie-break: lowest flattened index).
//
// Round 8 (post-mortem of rounds 6-7): any design where the 64 per-batch
// blocks re-scan the shared edge list pays ~64x redundant L2 traffic and
// regressed. The round-0 structure — each edge read ONCE, scattered to a
// global byte map (no init needed thanks to the 0xAA ws poison), then a tiny
// select — is traffic-optimal. This round keeps that structure and shaves
// its latency-bound parts:
//   * K1: 256 blocks x 64 threads (was 64x256) — 4x CU spread on a
//     latency-bound dependent load->store chain.
//   * K2: wave-parallel select — one coalesced 256 B load per batch, free
//     ranks via __shfl_up prefix sum, direct stores. No serial lane-0 scan.

// K1: copy edge_index into output (int4) AND scatter MAGIC bytes for
// same-batch edges, reusing the loaded registers.
__global__ __launch_bounds__(64) void copy_scatter_kernel(
    const int4* __restrict__ src4, const int4* __restrict__ dst4,
    int* __restrict__ out, unsigned char* __restrict__ exist)
{
    int i = blockIdx.x * 64 + threadIdx.x;           // 0..16383
    int4 s = src4[i];
    int4 d = dst4[i];
    ((int4*)(out))[i]        = s;                    // aug row 0 (src copy)
    ((int4*)(out + AUGE))[i] = d;                    // aug row 1 (dst copy)
    // scatter: exist[g*16384 + sl*128 + dl] = MAGIC for same-batch edges.
    // Racing identical byte stores are benign; byte stores are byte-granular.
    #define TRY(SS, DD)                                                   \
        {                                                                 \
            int gg = (SS) >> 7;                                           \
            if (((DD) >> 7) == gg)                                        \
                exist[(gg << 14) | (((SS) & 127) << 7) | ((DD) & 127)] =  \
                    (unsigned char)MAGIC;                                 \
        }
    TRY(s.x, d.x) TRY(s.y, d.y) TRY(s.z, d.z) TRY(s.w, d.w)
    #undef TRY
    if (i == 0) out[2 * AUGE] = BQ * TOPK;           // added_count = 1024
}

// K2: block g emits the first TOPK free non-diagonal pairs of batch g in
// row-major order. One wave per block: 64 lanes load 64 consecutive words
// (= 256 pairs, one coalesced 256 B transaction), compute per-lane free
// masks, prefix-sum ranks across the wave, and store rank<TOPK pairs
// directly. At ~6% exclusion density the first chunk always suffices; the
// outer loop is a correctness fallback covering all 16384 pairs.
__global__ __launch_bounds__(64) void select_kernel(
    const unsigned* __restrict__ exist_w, int* __restrict__ out)
{
    const int g    = blockIdx.x;                     // batch id
    const int lane = threadIdx.x;                    // 0..63
    const unsigned* w = exist_w + (g << 12);         // 4096 words per batch
    int found = 0;
    for (int base = 0; base < 4096 && found < TOPK; base += 64) {
        unsigned word = w[base + lane];
        // free mask over the 4 pairs in this word (byte != MAGIC, not diag)
        int fm = 0, cnt = 0;
        #pragma unroll
        for (int j = 0; j < 4; ++j) {
            int idx = ((base + lane) << 2) | j;      // flattened pair index
            int fr  = (((word >> (8 * j)) & 0xFFu) != MAGIC) &&
                      ((idx >> 7) != (idx & 127));
            fm |= fr << j;
            cnt += fr;
        }
        // inclusive wave prefix sum of cnt -> exclusive rank per lane
        int r = cnt;
        #pragma unroll
        for (int off = 1; off < 64; off <<= 1) {
            int v = __shfl_up(r, off);
            if (lane >= off) r += v;
        }
        int total = __shfl(r, 63);                   // free pairs this chunk
        r = found + r - cnt;                         // this lane's start rank
        #pragma unroll
        for (int j = 0; j < 4; ++j) {
            if ((fm >> j) & 1) {
                if (r < TOPK) {
                    int idx = ((base + lane) << 2) | j;
                    out[NE        + (g << 4) + r] = (g << 7) | (idx >> 7);  // src
                    out[AUGE + NE + (g << 4) + r] = (g << 7) | (idx & 127); // dst
                }
                ++r;
            }
        }
        found += total;
    }
}

extern "C" void kernel_launch(void* const* d_in, const int* in_sizes, int n_in,
                              void* d_out, int out_size, void* d_ws, size_t ws_size,
                              hipStream_t stream) {
    // Input order per setup_inputs():
    // 0:h 1:q 2:W1 3:b1 4:W2 5:b2 6:gamma 7:beta 8:edge_index 9:node_batch 10:top_k
    const int* edge_index = (const int*)d_in[8];
    const int4* e_src4 = (const int4*)edge_index;          // edge_index[0]
    const int4* e_dst4 = (const int4*)(edge_index + NE);   // edge_index[1]

    int* out = (int*)d_out;               // int32 output, 2*AUGE + 1 elements
    unsigned char* exist = (unsigned char*)d_ws;   // 1 MiB byte array

    copy_scatter_kernel<<<dim3(256), dim3(64), 0, stream>>>(e_src4, e_dst4, out, exist);
    select_kernel<<<dim3(BQ), dim3(64), 0, stream>>>((const unsigned*)exist, out);
}

// Round 4
// 75.954 us; speedup vs baseline: 1.2156x; 1.0028x over previous
//
#include <hip/hip_runtime.h>

// Problem constants (fixed by the reference file)
#define BQ    64        // batches
#define NG    128       // nodes per batch
#define NE    65536     // input edges
#define TOPK  16
#define AUGE  (NE + BQ * TOPK)   // 66560 edges per row after augmentation
#define MAGIC 0x55u     // "edge exists" tag (ws poison is 0xAA, fresh is 0x00 — both read as free)

// Structural insight (verified, absmax 0 across all rounds): LayerNorm over
// the size-1 last axis makes scores == beta (constant) for ANY inputs — the
// MLP is dead code. top_k picks, per batch, the first TOPK row-major (sl,dl)
// pairs that are neither diagonal nor an existing same-batch edge
// (jax.lax.top_k tie-break: lowest flattened index).
//
// Round 9 (post-mortem of round 8 = 76.2 us, best): total is ~41 us harness
// ws-poison fill (82% HBM peak, uncontrollable) + ~31 us harness restore
// train + ~4 us ours. Last lever: K1's per-thread dependent chain
// {ld s, ld d, st s, st d, 4 scatters}. Split the three independent work
// items across 3x blocks (uniform role per block): copy-src / copy-dst /
// scatter. Per-thread chain halves; reads double to 1 MB (L2-trivial).
// K2 (wave-parallel prefix-sum select) unchanged from round 8.

// K1: 768 blocks x 64 threads.
//   blocks   0..255: copy src row   (1 int4 load + 1 int4 store / thread)
//   blocks 256..511: copy dst row   (1 int4 load + 1 int4 store / thread)
//   blocks 512..767: scatter MAGIC  (2 int4 loads + <=4 indep byte stores)
__global__ __launch_bounds__(64) void copy_scatter_kernel(
    const int4* __restrict__ src4, const int4* __restrict__ dst4,
    int* __restrict__ out, unsigned char* __restrict__ exist)
{
    int tid = blockIdx.x * 64 + threadIdx.x;         // 0..49151
    if (tid < 16384) {
        ((int4*)(out))[tid] = src4[tid];             // aug row 0 (src copy)
        if (tid == 0) out[2 * AUGE] = BQ * TOPK;     // added_count = 1024
    } else if (tid < 32768) {
        int i = tid - 16384;
        ((int4*)(out + AUGE))[i] = dst4[i];          // aug row 1 (dst copy)
    } else {
        int i  = tid - 32768;                        // 0..16383
        int4 s = src4[i];
        int4 d = dst4[i];
        // exist[g*16384 + sl*128 + dl] = MAGIC for same-batch edges.
        // Racing identical byte stores are benign (byte-granular).
        #define TRY(SS, DD)                                                  \
            {                                                                \
                int gg = (SS) >> 7;                                          \
                if (((DD) >> 7) == gg)                                       \
                    exist[(gg << 14) | (((SS) & 127) << 7) | ((DD) & 127)] = \
                        (unsigned char)MAGIC;                                \
            }
        TRY(s.x, d.x) TRY(s.y, d.y) TRY(s.z, d.z) TRY(s.w, d.w)
        #undef TRY
    }
}

// K2: block g emits the first TOPK free non-diagonal pairs of batch g in
// row-major order. One wave per block: 64 lanes load 64 consecutive words
// (= 256 pairs, one coalesced 256 B transaction), compute per-lane free
// masks, prefix-sum ranks across the wave, and store rank<TOPK pairs
// directly. At ~6% exclusion density the first chunk always suffices; the
// outer loop is a correctness fallback covering all 16384 pairs.
__global__ __launch_bounds__(64) void select_kernel(
    const unsigned* __restrict__ exist_w, int* __restrict__ out)
{
    const int g    = blockIdx.x;                     // batch id
    const int lane = threadIdx.x;                    // 0..63
    const unsigned* w = exist_w + (g << 12);         // 4096 words per batch
    int found = 0;
    for (int base = 0; base < 4096 && found < TOPK; base += 64) {
        unsigned word = w[base + lane];
        // free mask over the 4 pairs in this word (byte != MAGIC, not diag)
        int fm = 0, cnt = 0;
        #pragma unroll
        for (int j = 0; j < 4; ++j) {
            int idx = ((base + lane) << 2) | j;      // flattened pair index
            int fr  = (((word >> (8 * j)) & 0xFFu) != MAGIC) &&
                      ((idx >> 7) != (idx & 127));
            fm |= fr << j;
            cnt += fr;
        }
        // inclusive wave prefix sum of cnt -> exclusive rank per lane
        int r = cnt;
        #pragma unroll
        for (int off = 1; off < 64; off <<= 1) {
            int v = __shfl_up(r, off);
            if (lane >= off) r += v;
        }
        int total = __shfl(r, 63);                   // free pairs this chunk
        r = found + r - cnt;                         // this lane's start rank
        #pragma unroll
        for (int j = 0; j < 4; ++j) {
            if ((fm >> j) & 1) {
                if (r < TOPK) {
                    int idx = ((base + lane) << 2) | j;
                    out[NE        + (g << 4) + r] = (g << 7) | (idx >> 7);  // src
                    out[AUGE + NE + (g << 4) + r] = (g << 7) | (idx & 127); // dst
                }
                ++r;
            }
        }
        found += total;
    }
}

extern "C" void kernel_launch(void* const* d_in, const int* in_sizes, int n_in,
                              void* d_out, int out_size, void* d_ws, size_t ws_size,
                              hipStream_t stream) {
    // Input order per setup_inputs():
    // 0:h 1:q 2:W1 3:b1 4:W2 5:b2 6:gamma 7:beta 8:edge_index 9:node_batch 10:top_k
    const int* edge_index = (const int*)d_in[8];
    const int4* e_src4 = (const int4*)edge_index;          // edge_index[0]
    const int4* e_dst4 = (const int4*)(edge_index + NE);   // edge_index[1]

    int* out = (int*)d_out;               // int32 output, 2*AUGE + 1 elements
    unsigned char* exist = (unsigned char*)d_ws;   // 1 MiB byte array

    copy_scatter_kernel<<<dim3(768), dim3(64), 0, stream>>>(e_src4, e_dst4, out, exist);
    select_kernel<<<dim3(BQ), dim3(64), 0, stream>>>((const unsigned*)exist, out);
}